// Round 1
// baseline (850.462 us; speedup 1.0000x reference)
//
#include <hip/hip_runtime.h>

// B=32, H=W=112 (HW=12544), C=256, K_TOP=128.
// out[b,h,w,c] = x[b,h,w,c] * mask[b,c], mask = top-128 channels of
// (mean_hw(x) @ W + b); sigmoid monotone -> rank pre-activation.
//
// Structure: mask[b] depends ONLY on x[b] (12.8 MB), so process batches in
// groups of 8 (103 MB -- fits L3 with 2.5x headroom):
//   pool(g) -> score(g) -> apply(g),  g = 0..3
// The apply pass of group g re-reads exactly the bytes pool(g) just streamed
// through L3 -> apply reads are L3/L2 hits, not HBM. HBM traffic drops from
// ~977 MB (monolithic + reverse-order trick) to ~822 MB (x once + out once).
// apply uses PLAIN loads (NT hint removed so nothing blocks cache service)
// and NT stores (out is never re-read; don't evict the group from L3).
// Within each chunk apply iterates k reversed: all 1568 blocks of a group are
// co-resident, so each block's chunk TAIL is the freshest data in its XCD's
// L2; same grid size + same blockIdx->chunk mapping repeats the XCD binding.

#define BB 32
#define CC 256
#define HW 12544
#define RPB 196                 // chunks per batch sample
#define F4_PER_CHUNK 4096       // 256 threads * 16 float4 = 64 KB
#define GB 8                    // batches per group (8 * 12.8 MB = 103 MB < L3)
#define NGROUPS (BB / GB)       // 4
#define BLKS_PER_GROUP (GB * RPB)  // 1568 (< 2048 co-residency: whole group resident)

typedef float nfloat4 __attribute__((ext_vector_type(4)));  // native vec for NT st

// ---------------- Kernel 1: pooled channel sums (atomic), one group ---------
__global__ __launch_bounds__(256) void pool_atomic(const float4* __restrict__ x4,
                                                   float* __restrict__ pooled_sum,
                                                   int chunk0) {
    const int chunk = chunk0 + blockIdx.x;
    const int b = chunk / RPB;
    const long base = (long)chunk * F4_PER_CHUNK;
    const int t = threadIdx.x;

    float4 acc = make_float4(0.f, 0.f, 0.f, 0.f);
#pragma unroll
    for (int k = 0; k < 16; ++k) {
        float4 v = x4[base + t + k * 256];
        acc.x += v.x; acc.y += v.y; acc.z += v.z; acc.w += v.w;
    }

    __shared__ float4 lds[256];
    lds[t] = acc;
    __syncthreads();

    if (t < 64) {
        float4 a = lds[t], b4 = lds[t + 64], c4 = lds[t + 128], d4 = lds[t + 192];
        float* dst = pooled_sum + b * CC + t * 4;   // 2048 hot addrs/group, 196 adds each
        atomicAdd(dst + 0, a.x + b4.x + c4.x + d4.x);
        atomicAdd(dst + 1, a.y + b4.y + c4.y + d4.y);
        atomicAdd(dst + 2, a.z + b4.z + c4.z + d4.z);
        atomicAdd(dst + 3, a.w + b4.w + c4.w + d4.w);
    }
}

// ---------------- Kernel 2: scores + rank-based top-k mask, one group -------
__global__ __launch_bounds__(256) void score_topk(const float* __restrict__ pooled_sum,
                                                  const float* __restrict__ Wm,
                                                  const float* __restrict__ bias,
                                                  float* __restrict__ maskf,
                                                  int batch0) {
    const int b = batch0 + blockIdx.x;
    const int c = threadIdx.x;
    __shared__ float p[CC];
    __shared__ float s[CC];

    p[c] = pooled_sum[b * CC + c] * (1.0f / (float)HW);
    __syncthreads();

    float acc = bias[c];
#pragma unroll 16
    for (int k = 0; k < CC; ++k) {
        acc += p[k] * Wm[k * CC + c];   // coalesced across threads; W L2/L3-hot
    }
    s[c] = acc;                          // sigmoid monotone: rank acc
    __syncthreads();

    int cnt = 0;
    const float sc = acc;
#pragma unroll 16
    for (int j = 0; j < CC; ++j) {
        float sj = s[j];                 // LDS broadcast
        cnt += (sj > sc) || (sj == sc && j < c);
    }
    maskf[b * CC + c] = (cnt < (CC / 2)) ? 1.0f : 0.0f;
}

// ---------------- Kernel 3: mask multiply over the L3-resident group --------
__global__ __launch_bounds__(256) void apply_mask(const float4* __restrict__ x4,
                                                  const float* __restrict__ maskf,
                                                  nfloat4* __restrict__ out4,
                                                  int chunk0) {
    const int chunk = chunk0 + blockIdx.x;   // same chunk->block mapping as pool
    const int b = chunk / RPB;
    const long base = (long)chunk * F4_PER_CHUNK;
    const int t = threadIdx.x;

    const float4 m = *(const float4*)(maskf + b * CC + (t & 63) * 4);

#pragma unroll
    for (int kk = 0; kk < 16; ++kk) {
        const int k = 15 - kk;                      // tail first: L2-resident
        const long i = base + t + k * 256;
        float4 v = x4[i];                           // plain load -> L2/L3 service
        nfloat4 r;
        r.x = v.x * m.x; r.y = v.y * m.y; r.z = v.z * m.z; r.w = v.w * m.w;
        __builtin_nontemporal_store(r, &out4[i]);   // out never re-read
    }
}

extern "C" void kernel_launch(void* const* d_in, const int* in_sizes, int n_in,
                              void* d_out, int out_size, void* d_ws, size_t ws_size,
                              hipStream_t stream) {
    const float* x  = (const float*)d_in[0];
    const float* Wm = (const float*)d_in[1];
    const float* bs = (const float*)d_in[2];
    float* out = (float*)d_out;

    float* pooled_sum = (float*)d_ws;                 // [32*256] f32 = 32 KB
    float* maskf      = (float*)d_ws + BB * CC;       // [32*256] f32

    // ws is poisoned 0xAA each call -> zero the atomic accumulator (32 KB, ~µs).
    hipMemsetAsync(pooled_sum, 0, BB * CC * sizeof(float), stream);

    for (int g = 0; g < NGROUPS; ++g) {
        const int chunk0 = g * BLKS_PER_GROUP;
        pool_atomic<<<BLKS_PER_GROUP, 256, 0, stream>>>((const float4*)x, pooled_sum, chunk0);
        score_topk<<<GB, 256, 0, stream>>>(pooled_sum, Wm, bs, maskf, g * GB);
        apply_mask<<<BLKS_PER_GROUP, 256, 0, stream>>>((const float4*)x, maskf,
                                                       (nfloat4*)out, chunk0);
    }
}